// Round 10
// baseline (611.173 us; speedup 1.0000x reference)
//
#include <hip/hip_runtime.h>

#define DEVINL __device__ __forceinline__

typedef __attribute__((ext_vector_type(8))) __bf16 bf16x8;
typedef __attribute__((ext_vector_type(4))) float f32x4;
typedef __attribute__((ext_vector_type(8))) unsigned short u16x8;

DEVINL unsigned short f2bf(float x) {
  unsigned u = __builtin_bit_cast(unsigned, x);
  u += 0x7FFFu + ((u >> 16) & 1u);
  return (unsigned short)(u >> 16);
}

#define BARRIER() asm volatile("s_barrier" ::: "memory")

template <int N>
DEVINL void waitvm() {
  asm volatile("s_waitcnt vmcnt(%0)" ::"n"(N) : "memory");
}

DEVINL void gload16(const void* g, void* l) {
  __builtin_amdgcn_global_load_lds(
      (const __attribute__((address_space(1))) void*)g,
      (__attribute__((address_space(3))) void*)l, 16, 0, 0);
}

// ---------------- prep: downsample mean + residual (bf16) ----------------
__global__ __launch_bounds__(256) void prep_kernel(
    const float* __restrict__ F, unsigned short* __restrict__ RES,
    float* __restrict__ DS, int n) {
  const int t = threadIdx.x;
  const int row = blockIdx.x * 16 + (t >> 4);
  const int cg = t & 15;
  if (row >= n) return;
  const float4* f4 = (const float4*)(F + (size_t)row * 128 + cg * 8);
  float4 v0 = f4[0], v1 = f4[1];
  float v[8] = {v0.x, v0.y, v0.z, v0.w, v1.x, v1.y, v1.z, v1.w};
  float s[8] = {v0.x, v0.y, v0.z, v0.w, v1.x, v1.y, v1.z, v1.w};
#pragma unroll
  for (int i = 0; i < 8; ++i) s[i] += __shfl_xor(s[i], 4);
#pragma unroll
  for (int i = 0; i < 8; ++i) s[i] += __shfl_xor(s[i], 8);
  u16x8 rb;
#pragma unroll
  for (int i = 0; i < 8; ++i) rb[i] = f2bf(v[i] - 0.25f * s[i]);
  *(u16x8*)(RES + (size_t)row * 128 + cg * 8) = rb;
  if (cg < 4) {
    float4 d0 = {0.25f * s[0], 0.25f * s[1], 0.25f * s[2], 0.25f * s[3]};
    float4 d1 = {0.25f * s[4], 0.25f * s[5], 0.25f * s[6], 0.25f * s[7]};
    float4* dp = (float4*)(DS + (size_t)row * 32 + cg * 8);
    dp[0] = d0;
    dp[1] = d1;
  }
}

// ---------------- weight pack: B-fragment layout, bf16 ----------------
template <int CIN, int COUT>
DEVINL void pack_one(const float* __restrict__ W, unsigned short* __restrict__ P, int g) {
  const int n = g % COUT;
  const int t = g / COUT;
  const int q = t & 3;
  const int t2 = t >> 2;
  const int ks = t2 % (CIN / 32);
  const int k = t2 / (CIN / 32);
  const float* src = W + ((size_t)k * CIN + ks * 32 + q * 8) * COUT + n;
  unsigned short* dst = P + (size_t)g * 8;
#pragma unroll
  for (int j = 0; j < 8; ++j) dst[j] = f2bf(src[(size_t)j * COUT]);
}

__global__ __launch_bounds__(256) void pack_kernel(
    const float* __restrict__ W0, const float* __restrict__ W1,
    const float* __restrict__ W2, unsigned short* __restrict__ P0,
    unsigned short* __restrict__ P1, unsigned short* __restrict__ P2) {
  int g = blockIdx.x * 256 + threadIdx.x;
  if (g < 55296)
    pack_one<128, 128>(W0, P0, g);
  else if (g < 69120)
    pack_one<128, 32>(W1, P1, g - 55296);
  else if (g < 72576)
    pack_one<32, 32>(W2, P2, g - 69120);
}

// ---------------- zero row N of the gather sources ----------------
__global__ void zero_tail(unsigned short* a, unsigned short* b, unsigned short* c) {
  int t = threadIdx.x;
  if (t < 128) { a[t] = 0; b[t] = 0; }
  if (t < 32) c[t] = 0;
}

// ---------------- gather-GEMM sparse conv ----------------
// Generalized round-5 structure, prefetch depth PF:
//  A: PF+1 LDS buffers via global_load_lds (pre-swizzled source).
//  B: per-wave REGISTER slice, double-buffered, one step ahead (L2-hot).
//  Counted waitvm<NB + PF*APF> keeps prefetches in flight across barriers.
//  28th IdxS row (zero-row) + clamped B-k make the tail branch-free.
// conv0 config (BM=64, WM=2, WN=2): halves A-LDS read redundancy (each wave
// reads its 32-row half once) AND halves acc to 32 AGPRs, so double-buffered
// B (NB=8 -> 64 VGPR) fits the 170-reg/3-waves-per-SIMD budget — the cell
// rounds 6/7 could not reach (round 7's spill was acc=64 at BM=128).
template <int CIN, int COUT, int BK, int BM, int PF, int WM, int WN, bool FINAL,
          int MINB>
__global__ __launch_bounds__(256, MINB) void spconv(
    const unsigned short* __restrict__ X, const unsigned short* __restrict__ Bp,
    const int* __restrict__ nbr, unsigned short* __restrict__ Y,
    float* __restrict__ OUT, const float* __restrict__ DS, int nr) {
  constexpr int H = CIN / BK;
  constexpr int S = 27 * H;
  constexpr int NBUF = PF + 1;
  constexpr int KSL = BK / 32;
  constexpr int WROWS = BM / WM;
  constexpr int WCOLS = COUT / WN;
  constexpr int MF = WROWS / 16;
  constexpr int NF = WCOLS / 16;
  constexpr int CPR = BK / 8;
  constexpr int SWZ = (CPR < 8 ? CPR - 1 : 7);
  constexpr int RB = BK * 2;
  constexpr int APF = BM * CPR / 256;
  constexpr int NB = KSL * NF;

  __shared__ unsigned short As[NBUF][BM * BK];
  __shared__ int IdxS[28 * BM];  // row 27 = zero-row dummy for uniform tail

  const int tid = threadIdx.x;
  const int lane = tid & 63;
  const int wave = tid >> 6;
  const int wm = wave / WN;
  const int wn = wave % WN;
  const int base = blockIdx.x * BM;
  const int q = lane >> 4;
  const int l16 = lane & 15;

  for (int f = tid; f < 28 * BM; f += 256) {
    int k = f / BM;
    int nn = base + (f % BM);
    IdxS[f] = (k < 27 && nn < nr) ? nbr[(size_t)k * nr + nn] : nr;
  }
  __syncthreads();  // clean vmcnt baseline before the pipeline

  const unsigned short* bbase = Bp + ((size_t)q * COUT + wn * WCOLS + l16) * 8;

  bf16x8 bA[NB], bB[NB];

  auto loadB = [&](bf16x8(&dst)[NB], int s) {
    const int k0 = s / H;
    const int k = (k0 > 26) ? 26 : k0;  // clamp dummy steps (regs never used)
    const int hh = s % H;
#pragma unroll
    for (int ks = 0; ks < KSL; ++ks)
#pragma unroll
      for (int j = 0; j < NF; ++j) {
        const int ksg = hh * KSL + ks;
        dst[ks * NF + j] = *(const bf16x8*)(
            bbase + ((size_t)k * CIN * COUT) + ((size_t)(ksg * 4) * COUT + j * 16) * 8);
      }
  };

  auto issueA = [&](int s) {
    const int k = s / H;        // k==27 hits the dummy zero-row idx row
    const int hh = s % H;
    const int kb = s % NBUF;
#pragma unroll
    for (int pp = 0; pp < APF; ++pp) {
      int slot = pp * 256 + tid;
      int r = slot / CPR;
      int cc = (slot % CPR) * 16;
      int csw = cc ^ ((r & SWZ) << 4);
      int g = IdxS[k * BM + r];
      gload16(X + (size_t)g * CIN + hh * BK + (csw >> 1),
              (char*)(&As[kb][0]) + slot * 16);
    }
  };

  f32x4 acc[MF][NF] = {};

  auto mfmaStep = [&](int kb, const bf16x8(&bf)[NB]) {
    const char* Ab = (const char*)(&As[kb][0]);
#pragma unroll
    for (int ks = 0; ks < KSL; ++ks) {
      bf16x8 af[MF];
#pragma unroll
      for (int i = 0; i < MF; ++i) {
        int r = wm * WROWS + i * 16 + l16;
        int db = r * RB + (((ks * 64 + q * 16) & (RB - 1)) ^ ((r & SWZ) << 4));
        af[i] = __builtin_bit_cast(bf16x8, *(const uint4*)(Ab + db));
      }
#pragma unroll
      for (int i = 0; i < MF; ++i)
#pragma unroll
        for (int j = 0; j < NF; ++j)
          acc[i][j] = __builtin_amdgcn_mfma_f32_16x16x32_bf16(af[i], bf[ks * NF + j],
                                                              acc[i][j], 0, 0, 0);
    }
  };

  // ---- prologue: A(0..PF-1) + B(0) in flight ----
  issueA(0);
  loadB(bA, 0);
  if constexpr (PF >= 2) issueA(1);

#pragma unroll 1
  for (int s = 0; s + 1 < S; s += 2) {
    // ---- even half: compute s, issue A(s+PF), B(s+1) ----
    loadB(bB, s + 1);
    issueA(s + PF);
    waitvm<NB + PF * APF>();  // A(s)+B(s) landed; deeper prefetches in flight
    BARRIER();
    mfmaStep(s % NBUF, bA);
    BARRIER();
    // ---- odd half: compute s+1, issue A(s+1+PF), B(s+2) ----
    loadB(bA, s + 2);
    issueA(s + 1 + PF);
    waitvm<NB + PF * APF>();
    BARRIER();
    mfmaStep((s + 1) % NBUF, bB);
    BARRIER();
  }
  waitvm<0>();  // drain dummy issues (LDS dealloc safety)
  if constexpr (S & 1) {
    BARRIER();
    mfmaStep((S - 1) % NBUF, bA);
  }

  // ---- epilogue: C layout col=lane&15, row=(lane>>4)*4+reg ----
#pragma unroll
  for (int i = 0; i < MF; ++i)
#pragma unroll
    for (int j = 0; j < NF; ++j)
#pragma unroll
      for (int r = 0; r < 4; ++r) {
        int row = base + wm * WROWS + i * 16 + q * 4 + r;
        int col = wn * WCOLS + j * 16 + l16;
        if (row < nr) {
          float v = acc[i][j][r];
          if constexpr (FINAL)
            OUT[(size_t)row * COUT + col] = v + DS[(size_t)row * COUT + col];
          else
            Y[(size_t)row * COUT + col] = f2bf(v);
        }
      }
}

// ---------------- launch ----------------
extern "C" void kernel_launch(void* const* d_in, const int* in_sizes, int n_in,
                              void* d_out, int out_size, void* d_ws, size_t ws_size,
                              hipStream_t stream) {
  const float* feats = (const float*)d_in[0];
  const float* W0 = (const float*)d_in[1];
  const float* W1 = (const float*)d_in[2];
  const float* W2 = (const float*)d_in[3];
  const int* nbr = (const int*)d_in[4];
  const int n = in_sizes[0] / 128;
  float* out = (float*)d_out;

  char* p = (char*)d_ws;
  auto take = [&](size_t bytes) {
    char* r = p;
    p += (bytes + 255) & ~(size_t)255;
    return r;
  };
  unsigned short* resB = (unsigned short*)take((size_t)(n + 1) * 128 * 2);
  unsigned short* y0 = (unsigned short*)take((size_t)(n + 1) * 128 * 2);
  unsigned short* y1 = (unsigned short*)take((size_t)(n + 1) * 32 * 2);
  float* ds = (float*)take((size_t)n * 32 * 4);
  unsigned short* p0 = (unsigned short*)take((size_t)27 * 128 * 128 * 2);
  unsigned short* p1 = (unsigned short*)take((size_t)27 * 128 * 32 * 2);
  unsigned short* p2 = (unsigned short*)take((size_t)27 * 32 * 32 * 2);

  prep_kernel<<<(n + 15) / 16, 256, 0, stream>>>(feats, resB, ds, n);
  pack_kernel<<<284, 256, 0, stream>>>(W0, W1, W2, p0, p1, p2);
  zero_tail<<<1, 128, 0, stream>>>(resB + (size_t)n * 128, y0 + (size_t)n * 128,
                                   y1 + (size_t)n * 32);
  const int gb64 = (n + 63) / 64;
  const int gb128 = (n + 127) / 128;
  // conv0: 128->128. BM=64, WM=2/WN=2, double-buffered B, PF=1:
  // A-LDS reads 16KB/step (was 32), acc=32 AGPR + B=64 VGPR -> ~140 regs,
  // fits 3 waves/SIMD. LDS 23.5KB.
  spconv<128, 128, 64, 64, 1, 2, 2, false, 3>
      <<<gb64, 256, 0, stream>>>(resB, p0, nbr, y0, nullptr, nullptr, n);
  // conv1: 128->32. Round-5/9 proven: BM=128, BK=64, PF=1, WM=4/WN=1.
  spconv<128, 32, 64, 128, 1, 4, 1, false, 3>
      <<<gb128, 256, 0, stream>>>(y0, p1, nbr, y1, nullptr, nullptr, n);
  // conv2: 32->32. Round-5/9 proven: BM=128, BK=32, PF=1, WM=4/WN=1.
  spconv<32, 32, 32, 128, 1, 4, 1, true, 4>
      <<<gb128, 256, 0, stream>>>(y1, p2, nbr, nullptr, out, ds, n);
}

// Round 11
// 531.120 us; speedup vs baseline: 1.1507x; 1.1507x over previous
//
#include <hip/hip_runtime.h>

#define DEVINL __device__ __forceinline__

typedef __attribute__((ext_vector_type(8))) __bf16 bf16x8;
typedef __attribute__((ext_vector_type(4))) float f32x4;
typedef __attribute__((ext_vector_type(8))) unsigned short u16x8;

DEVINL unsigned short f2bf(float x) {
  unsigned u = __builtin_bit_cast(unsigned, x);
  u += 0x7FFFu + ((u >> 16) & 1u);
  return (unsigned short)(u >> 16);
}

#define BARRIER() asm volatile("s_barrier" ::: "memory")

template <int N>
DEVINL void waitvm() {
  asm volatile("s_waitcnt vmcnt(%0)" ::"n"(N) : "memory");
}

DEVINL void gload16(const void* g, void* l) {
  __builtin_amdgcn_global_load_lds(
      (const __attribute__((address_space(1))) void*)g,
      (__attribute__((address_space(3))) void*)l, 16, 0, 0);
}

// ---------------- prep: downsample mean + residual (bf16) ----------------
__global__ __launch_bounds__(256) void prep_kernel(
    const float* __restrict__ F, unsigned short* __restrict__ RES,
    float* __restrict__ DS, int n) {
  const int t = threadIdx.x;
  const int row = blockIdx.x * 16 + (t >> 4);
  const int cg = t & 15;
  if (row >= n) return;
  const float4* f4 = (const float4*)(F + (size_t)row * 128 + cg * 8);
  float4 v0 = f4[0], v1 = f4[1];
  float v[8] = {v0.x, v0.y, v0.z, v0.w, v1.x, v1.y, v1.z, v1.w};
  float s[8] = {v0.x, v0.y, v0.z, v0.w, v1.x, v1.y, v1.z, v1.w};
#pragma unroll
  for (int i = 0; i < 8; ++i) s[i] += __shfl_xor(s[i], 4);
#pragma unroll
  for (int i = 0; i < 8; ++i) s[i] += __shfl_xor(s[i], 8);
  u16x8 rb;
#pragma unroll
  for (int i = 0; i < 8; ++i) rb[i] = f2bf(v[i] - 0.25f * s[i]);
  *(u16x8*)(RES + (size_t)row * 128 + cg * 8) = rb;
  if (cg < 4) {
    float4 d0 = {0.25f * s[0], 0.25f * s[1], 0.25f * s[2], 0.25f * s[3]};
    float4 d1 = {0.25f * s[4], 0.25f * s[5], 0.25f * s[6], 0.25f * s[7]};
    float4* dp = (float4*)(DS + (size_t)row * 32 + cg * 8);
    dp[0] = d0;
    dp[1] = d1;
  }
}

// ---------------- weight pack: B-fragment layout, bf16 ----------------
template <int CIN, int COUT>
DEVINL void pack_one(const float* __restrict__ W, unsigned short* __restrict__ P, int g) {
  const int n = g % COUT;
  const int t = g / COUT;
  const int q = t & 3;
  const int t2 = t >> 2;
  const int ks = t2 % (CIN / 32);
  const int k = t2 / (CIN / 32);
  const float* src = W + ((size_t)k * CIN + ks * 32 + q * 8) * COUT + n;
  unsigned short* dst = P + (size_t)g * 8;
#pragma unroll
  for (int j = 0; j < 8; ++j) dst[j] = f2bf(src[(size_t)j * COUT]);
}

__global__ __launch_bounds__(256) void pack_kernel(
    const float* __restrict__ W0, const float* __restrict__ W1,
    const float* __restrict__ W2, unsigned short* __restrict__ P0,
    unsigned short* __restrict__ P1, unsigned short* __restrict__ P2) {
  int g = blockIdx.x * 256 + threadIdx.x;
  if (g < 55296)
    pack_one<128, 128>(W0, P0, g);
  else if (g < 69120)
    pack_one<128, 32>(W1, P1, g - 55296);
  else if (g < 72576)
    pack_one<32, 32>(W2, P2, g - 69120);
}

// ---------------- zero row N of the gather sources ----------------
__global__ void zero_tail(unsigned short* a, unsigned short* b, unsigned short* c) {
  int t = threadIdx.x;
  if (t < 128) { a[t] = 0; b[t] = 0; }
  if (t < 32) c[t] = 0;
}

// ---------------- gather-GEMM sparse conv ----------------
// Generalized round-5 structure, prefetch depth PF:
//  A: PF+1 LDS buffers via global_load_lds (pre-swizzled source).
//  B: per-wave REGISTER slice, double-buffered, one step ahead (L2-hot).
//  Counted waitvm<NB + PF*APF> keeps prefetches in flight across barriers.
//  28th IdxS row (zero-row) + clamped B-k make the tail branch-free.
// conv0 config (BM=128, WM=2/WN=2, MINB=2): the balanced tiling cell.
//  A-LDS reads 32KB/step (vs 64 at WN=4), B-L2 32KB/step (vs 16) at
//  UNCHANGED block count. Needs ~180 regs -> launch_bounds(256,2) so the
//  allocator is NOT capped at 170 (round-7's spill cause). 2 blocks/CU;
//  rounds 0/8/9 showed blocks/CU in 2..4 is perf-neutral for this loop.
template <int CIN, int COUT, int BK, int BM, int PF, int WM, int WN, bool FINAL,
          int MINB>
__global__ __launch_bounds__(256, MINB) void spconv(
    const unsigned short* __restrict__ X, const unsigned short* __restrict__ Bp,
    const int* __restrict__ nbr, unsigned short* __restrict__ Y,
    float* __restrict__ OUT, const float* __restrict__ DS, int nr) {
  constexpr int H = CIN / BK;
  constexpr int S = 27 * H;
  constexpr int NBUF = PF + 1;
  constexpr int KSL = BK / 32;
  constexpr int WROWS = BM / WM;
  constexpr int WCOLS = COUT / WN;
  constexpr int MF = WROWS / 16;
  constexpr int NF = WCOLS / 16;
  constexpr int CPR = BK / 8;
  constexpr int SWZ = (CPR < 8 ? CPR - 1 : 7);
  constexpr int RB = BK * 2;
  constexpr int APF = BM * CPR / 256;
  constexpr int NB = KSL * NF;

  __shared__ unsigned short As[NBUF][BM * BK];
  __shared__ int IdxS[28 * BM];  // row 27 = zero-row dummy for uniform tail

  const int tid = threadIdx.x;
  const int lane = tid & 63;
  const int wave = tid >> 6;
  const int wm = wave / WN;
  const int wn = wave % WN;
  const int base = blockIdx.x * BM;
  const int q = lane >> 4;
  const int l16 = lane & 15;

  for (int f = tid; f < 28 * BM; f += 256) {
    int k = f / BM;
    int nn = base + (f % BM);
    IdxS[f] = (k < 27 && nn < nr) ? nbr[(size_t)k * nr + nn] : nr;
  }
  __syncthreads();  // clean vmcnt baseline before the pipeline

  const unsigned short* bbase = Bp + ((size_t)q * COUT + wn * WCOLS + l16) * 8;

  bf16x8 bA[NB], bB[NB];

  auto loadB = [&](bf16x8(&dst)[NB], int s) {
    const int k0 = s / H;
    const int k = (k0 > 26) ? 26 : k0;  // clamp dummy steps (regs never used)
    const int hh = s % H;
#pragma unroll
    for (int ks = 0; ks < KSL; ++ks)
#pragma unroll
      for (int j = 0; j < NF; ++j) {
        const int ksg = hh * KSL + ks;
        dst[ks * NF + j] = *(const bf16x8*)(
            bbase + ((size_t)k * CIN * COUT) + ((size_t)(ksg * 4) * COUT + j * 16) * 8);
      }
  };

  auto issueA = [&](int s) {
    const int k = s / H;        // k==27 hits the dummy zero-row idx row
    const int hh = s % H;
    const int kb = s % NBUF;
#pragma unroll
    for (int pp = 0; pp < APF; ++pp) {
      int slot = pp * 256 + tid;
      int r = slot / CPR;
      int cc = (slot % CPR) * 16;
      int csw = cc ^ ((r & SWZ) << 4);
      int g = IdxS[k * BM + r];
      gload16(X + (size_t)g * CIN + hh * BK + (csw >> 1),
              (char*)(&As[kb][0]) + slot * 16);
    }
  };

  f32x4 acc[MF][NF] = {};

  auto mfmaStep = [&](int kb, const bf16x8(&bf)[NB]) {
    const char* Ab = (const char*)(&As[kb][0]);
#pragma unroll
    for (int ks = 0; ks < KSL; ++ks) {
      bf16x8 af[MF];
#pragma unroll
      for (int i = 0; i < MF; ++i) {
        int r = wm * WROWS + i * 16 + l16;
        int db = r * RB + (((ks * 64 + q * 16) & (RB - 1)) ^ ((r & SWZ) << 4));
        af[i] = __builtin_bit_cast(bf16x8, *(const uint4*)(Ab + db));
      }
#pragma unroll
      for (int i = 0; i < MF; ++i)
#pragma unroll
        for (int j = 0; j < NF; ++j)
          acc[i][j] = __builtin_amdgcn_mfma_f32_16x16x32_bf16(af[i], bf[ks * NF + j],
                                                              acc[i][j], 0, 0, 0);
    }
  };

  // ---- prologue: A(0..PF-1) + B(0) in flight ----
  issueA(0);
  loadB(bA, 0);
  if constexpr (PF >= 2) issueA(1);

#pragma unroll 1
  for (int s = 0; s + 1 < S; s += 2) {
    // ---- even half: compute s, issue A(s+PF), B(s+1) ----
    loadB(bB, s + 1);
    issueA(s + PF);
    waitvm<NB + PF * APF>();  // A(s)+B(s) landed; deeper prefetches in flight
    BARRIER();
    mfmaStep(s % NBUF, bA);
    BARRIER();
    // ---- odd half: compute s+1, issue A(s+1+PF), B(s+2) ----
    loadB(bA, s + 2);
    issueA(s + 1 + PF);
    waitvm<NB + PF * APF>();
    BARRIER();
    mfmaStep((s + 1) % NBUF, bB);
    BARRIER();
  }
  waitvm<0>();  // drain dummy issues (LDS dealloc safety)
  if constexpr (S & 1) {
    BARRIER();
    mfmaStep((S - 1) % NBUF, bA);
  }

  // ---- epilogue: C layout col=lane&15, row=(lane>>4)*4+reg ----
#pragma unroll
  for (int i = 0; i < MF; ++i)
#pragma unroll
    for (int j = 0; j < NF; ++j)
#pragma unroll
      for (int r = 0; r < 4; ++r) {
        int row = base + wm * WROWS + i * 16 + q * 4 + r;
        int col = wn * WCOLS + j * 16 + l16;
        if (row < nr) {
          float v = acc[i][j][r];
          if constexpr (FINAL)
            OUT[(size_t)row * COUT + col] = v + DS[(size_t)row * COUT + col];
          else
            Y[(size_t)row * COUT + col] = f2bf(v);
        }
      }
}

// ---------------- launch ----------------
extern "C" void kernel_launch(void* const* d_in, const int* in_sizes, int n_in,
                              void* d_out, int out_size, void* d_ws, size_t ws_size,
                              hipStream_t stream) {
  const float* feats = (const float*)d_in[0];
  const float* W0 = (const float*)d_in[1];
  const float* W1 = (const float*)d_in[2];
  const float* W2 = (const float*)d_in[3];
  const int* nbr = (const int*)d_in[4];
  const int n = in_sizes[0] / 128;
  float* out = (float*)d_out;

  char* p = (char*)d_ws;
  auto take = [&](size_t bytes) {
    char* r = p;
    p += (bytes + 255) & ~(size_t)255;
    return r;
  };
  unsigned short* resB = (unsigned short*)take((size_t)(n + 1) * 128 * 2);
  unsigned short* y0 = (unsigned short*)take((size_t)(n + 1) * 128 * 2);
  unsigned short* y1 = (unsigned short*)take((size_t)(n + 1) * 32 * 2);
  float* ds = (float*)take((size_t)n * 32 * 4);
  unsigned short* p0 = (unsigned short*)take((size_t)27 * 128 * 128 * 2);
  unsigned short* p1 = (unsigned short*)take((size_t)27 * 128 * 32 * 2);
  unsigned short* p2 = (unsigned short*)take((size_t)27 * 32 * 32 * 2);

  prep_kernel<<<(n + 15) / 16, 256, 0, stream>>>(feats, resB, ds, n);
  pack_kernel<<<284, 256, 0, stream>>>(W0, W1, W2, p0, p1, p2);
  zero_tail<<<1, 128, 0, stream>>>(resB + (size_t)n * 128, y0 + (size_t)n * 128,
                                   y1 + (size_t)n * 32);
  const int gb128 = (n + 127) / 128;
  // conv0: 128->128. BM=128, WM=2/WN=2, double-B, MINB=2 (no 170-reg cap ->
  // no spill). A-LDS 32KB/step, B-L2 32KB/step, block count unchanged.
  spconv<128, 128, 64, 128, 1, 2, 2, false, 2>
      <<<gb128, 256, 0, stream>>>(resB, p0, nbr, y0, nullptr, nullptr, n);
  // conv1: 128->32. Round-5/9 proven: BM=128, BK=64, PF=1, WM=4/WN=1.
  spconv<128, 32, 64, 128, 1, 4, 1, false, 3>
      <<<gb128, 256, 0, stream>>>(y0, p1, nbr, y1, nullptr, nullptr, n);
  // conv2: 32->32. Round-5/9 proven: BM=128, BK=32, PF=1, WM=4/WN=1.
  spconv<32, 32, 32, 128, 1, 4, 1, true, 4>
      <<<gb128, 256, 0, stream>>>(y1, p2, nbr, nullptr, out, ds, n);
}

// Round 12
// 508.835 us; speedup vs baseline: 1.2011x; 1.0438x over previous
//
#include <hip/hip_runtime.h>

#define DEVINL __device__ __forceinline__

typedef __attribute__((ext_vector_type(8))) __bf16 bf16x8;
typedef __attribute__((ext_vector_type(4))) float f32x4;
typedef __attribute__((ext_vector_type(8))) unsigned short u16x8;

DEVINL unsigned short f2bf(float x) {
  unsigned u = __builtin_bit_cast(unsigned, x);
  u += 0x7FFFu + ((u >> 16) & 1u);
  return (unsigned short)(u >> 16);
}

#define BARRIER() asm volatile("s_barrier" ::: "memory")

template <int N>
DEVINL void waitvm() {
  asm volatile("s_waitcnt vmcnt(%0)" ::"n"(N) : "memory");
}

DEVINL void gload16(const void* g, void* l) {
  __builtin_amdgcn_global_load_lds(
      (const __attribute__((address_space(1))) void*)g,
      (__attribute__((address_space(3))) void*)l, 16, 0, 0);
}

// ---------------- prep: downsample mean + residual (bf16) ----------------
__global__ __launch_bounds__(256) void prep_kernel(
    const float* __restrict__ F, unsigned short* __restrict__ RES,
    float* __restrict__ DS, int n) {
  const int t = threadIdx.x;
  const int row = blockIdx.x * 16 + (t >> 4);
  const int cg = t & 15;
  if (row >= n) return;
  const float4* f4 = (const float4*)(F + (size_t)row * 128 + cg * 8);
  float4 v0 = f4[0], v1 = f4[1];
  float v[8] = {v0.x, v0.y, v0.z, v0.w, v1.x, v1.y, v1.z, v1.w};
  float s[8] = {v0.x, v0.y, v0.z, v0.w, v1.x, v1.y, v1.z, v1.w};
#pragma unroll
  for (int i = 0; i < 8; ++i) s[i] += __shfl_xor(s[i], 4);
#pragma unroll
  for (int i = 0; i < 8; ++i) s[i] += __shfl_xor(s[i], 8);
  u16x8 rb;
#pragma unroll
  for (int i = 0; i < 8; ++i) rb[i] = f2bf(v[i] - 0.25f * s[i]);
  *(u16x8*)(RES + (size_t)row * 128 + cg * 8) = rb;
  if (cg < 4) {
    float4 d0 = {0.25f * s[0], 0.25f * s[1], 0.25f * s[2], 0.25f * s[3]};
    float4 d1 = {0.25f * s[4], 0.25f * s[5], 0.25f * s[6], 0.25f * s[7]};
    float4* dp = (float4*)(DS + (size_t)row * 32 + cg * 8);
    dp[0] = d0;
    dp[1] = d1;
  }
}

// ---------------- weight pack: B-fragment layout, bf16 ----------------
template <int CIN, int COUT>
DEVINL void pack_one(const float* __restrict__ W, unsigned short* __restrict__ P, int g) {
  const int n = g % COUT;
  const int t = g / COUT;
  const int q = t & 3;
  const int t2 = t >> 2;
  const int ks = t2 % (CIN / 32);
  const int k = t2 / (CIN / 32);
  const float* src = W + ((size_t)k * CIN + ks * 32 + q * 8) * COUT + n;
  unsigned short* dst = P + (size_t)g * 8;
#pragma unroll
  for (int j = 0; j < 8; ++j) dst[j] = f2bf(src[(size_t)j * COUT]);
}

__global__ __launch_bounds__(256) void pack_kernel(
    const float* __restrict__ W0, const float* __restrict__ W1,
    const float* __restrict__ W2, unsigned short* __restrict__ P0,
    unsigned short* __restrict__ P1, unsigned short* __restrict__ P2) {
  int g = blockIdx.x * 256 + threadIdx.x;
  if (g < 55296)
    pack_one<128, 128>(W0, P0, g);
  else if (g < 69120)
    pack_one<128, 32>(W1, P1, g - 55296);
  else if (g < 72576)
    pack_one<32, 32>(W2, P2, g - 69120);
}

// ---------------- zero row N of the gather sources ----------------
__global__ void zero_tail(unsigned short* a, unsigned short* b, unsigned short* c) {
  int t = threadIdx.x;
  if (t < 128) { a[t] = 0; b[t] = 0; }
  if (t < 32) c[t] = 0;
}

// ---------------- gather-GEMM sparse conv (LDS-staged A; conv0) ----------------
// Round-5 proven structure (best measured: conv0 = 275 us): A double-buffered
// via global_load_lds (pre-swizzled source), B register dbuf one step ahead,
// counted waitvm, 2 barriers/step.
template <int CIN, int COUT, int BK, int BM, int PF, int WM, int WN, bool FINAL,
          int MINB>
__global__ __launch_bounds__(256, MINB) void spconv(
    const unsigned short* __restrict__ X, const unsigned short* __restrict__ Bp,
    const int* __restrict__ nbr, unsigned short* __restrict__ Y,
    float* __restrict__ OUT, const float* __restrict__ DS, int nr) {
  constexpr int H = CIN / BK;
  constexpr int S = 27 * H;
  constexpr int NBUF = PF + 1;
  constexpr int KSL = BK / 32;
  constexpr int WROWS = BM / WM;
  constexpr int WCOLS = COUT / WN;
  constexpr int MF = WROWS / 16;
  constexpr int NF = WCOLS / 16;
  constexpr int CPR = BK / 8;
  constexpr int SWZ = (CPR < 8 ? CPR - 1 : 7);
  constexpr int RB = BK * 2;
  constexpr int APF = BM * CPR / 256;
  constexpr int NB = KSL * NF;

  __shared__ unsigned short As[NBUF][BM * BK];
  __shared__ int IdxS[28 * BM];  // row 27 = zero-row dummy for uniform tail

  const int tid = threadIdx.x;
  const int lane = tid & 63;
  const int wave = tid >> 6;
  const int wm = wave / WN;
  const int wn = wave % WN;
  const int base = blockIdx.x * BM;
  const int q = lane >> 4;
  const int l16 = lane & 15;

  for (int f = tid; f < 28 * BM; f += 256) {
    int k = f / BM;
    int nn = base + (f % BM);
    IdxS[f] = (k < 27 && nn < nr) ? nbr[(size_t)k * nr + nn] : nr;
  }
  __syncthreads();  // clean vmcnt baseline before the pipeline

  const unsigned short* bbase = Bp + ((size_t)q * COUT + wn * WCOLS + l16) * 8;

  bf16x8 bA[NB], bB[NB];

  auto loadB = [&](bf16x8(&dst)[NB], int s) {
    const int k0 = s / H;
    const int k = (k0 > 26) ? 26 : k0;  // clamp dummy steps (regs never used)
    const int hh = s % H;
#pragma unroll
    for (int ks = 0; ks < KSL; ++ks)
#pragma unroll
      for (int j = 0; j < NF; ++j) {
        const int ksg = hh * KSL + ks;
        dst[ks * NF + j] = *(const bf16x8*)(
            bbase + ((size_t)k * CIN * COUT) + ((size_t)(ksg * 4) * COUT + j * 16) * 8);
      }
  };

  auto issueA = [&](int s) {
    const int k = s / H;        // k==27 hits the dummy zero-row idx row
    const int hh = s % H;
    const int kb = s % NBUF;
#pragma unroll
    for (int pp = 0; pp < APF; ++pp) {
      int slot = pp * 256 + tid;
      int r = slot / CPR;
      int cc = (slot % CPR) * 16;
      int csw = cc ^ ((r & SWZ) << 4);
      int g = IdxS[k * BM + r];
      gload16(X + (size_t)g * CIN + hh * BK + (csw >> 1),
              (char*)(&As[kb][0]) + slot * 16);
    }
  };

  f32x4 acc[MF][NF] = {};

  auto mfmaStep = [&](int kb, const bf16x8(&bf)[NB]) {
    const char* Ab = (const char*)(&As[kb][0]);
#pragma unroll
    for (int ks = 0; ks < KSL; ++ks) {
      bf16x8 af[MF];
#pragma unroll
      for (int i = 0; i < MF; ++i) {
        int r = wm * WROWS + i * 16 + l16;
        int db = r * RB + (((ks * 64 + q * 16) & (RB - 1)) ^ ((r & SWZ) << 4));
        af[i] = __builtin_bit_cast(bf16x8, *(const uint4*)(Ab + db));
      }
#pragma unroll
      for (int i = 0; i < MF; ++i)
#pragma unroll
        for (int j = 0; j < NF; ++j)
          acc[i][j] = __builtin_amdgcn_mfma_f32_16x16x32_bf16(af[i], bf[ks * NF + j],
                                                              acc[i][j], 0, 0, 0);
    }
  };

  // ---- prologue: A(0..PF-1) + B(0) in flight ----
  issueA(0);
  loadB(bA, 0);
  if constexpr (PF >= 2) issueA(1);

#pragma unroll 1
  for (int s = 0; s + 1 < S; s += 2) {
    loadB(bB, s + 1);
    issueA(s + PF);
    waitvm<NB + PF * APF>();  // A(s)+B(s) landed; deeper prefetches in flight
    BARRIER();
    mfmaStep(s % NBUF, bA);
    BARRIER();
    loadB(bA, s + 2);
    issueA(s + 1 + PF);
    waitvm<NB + PF * APF>();
    BARRIER();
    mfmaStep((s + 1) % NBUF, bB);
    BARRIER();
  }
  waitvm<0>();  // drain dummy issues (LDS dealloc safety)
  if constexpr (S & 1) {
    BARRIER();
    mfmaStep((S - 1) % NBUF, bA);
  }

#pragma unroll
  for (int i = 0; i < MF; ++i)
#pragma unroll
    for (int j = 0; j < NF; ++j)
#pragma unroll
      for (int r = 0; r < 4; ++r) {
        int row = base + wm * WROWS + i * 16 + q * 4 + r;
        int col = wn * WCOLS + j * 16 + l16;
        if (row < nr) {
          float v = acc[i][j][r];
          if constexpr (FINAL)
            OUT[(size_t)row * COUT + col] = v + DS[(size_t)row * COUT + col];
          else
            Y[(size_t)row * COUT + col] = f2bf(v);
        }
      }
}

// ---------------- register-gather sparse conv (conv1 / conv2) ----------------
// For WM=WAVES/WN=1 configs the row partition gives ZERO cross-wave A reuse,
// so LDS staging is pure overhead. Each wave gathers its MFMA A-fragments
// (contiguous 16B row slices — exactly the fragment layout) DIRECTLY to
// registers, double-buffered one step ahead. B register dbuf as proven.
// One barrier/step (no shared-LDS hazard; barrier pins issue order & pacing).
// Loads are compiler-visible -> dependency waits are compiler-guaranteed;
// waitvm batches them. Fragment values and accumulation order identical to
// the LDS path -> bit-identical results.
template <int CIN, int COUT, int BK, int BM, int WM, int WN, bool FINAL, int MINB>
__global__ __launch_bounds__(256, MINB) void spconv_reg(
    const unsigned short* __restrict__ X, const unsigned short* __restrict__ Bp,
    const int* __restrict__ nbr, unsigned short* __restrict__ Y,
    float* __restrict__ OUT, const float* __restrict__ DS, int nr) {
  constexpr int H = CIN / BK;
  constexpr int S = 27 * H;
  constexpr int KSL = BK / 32;
  constexpr int WROWS = BM / WM;
  constexpr int WCOLS = COUT / WN;
  constexpr int MF = WROWS / 16;
  constexpr int NF = WCOLS / 16;
  constexpr int NB = KSL * NF;   // B loads per lane per step
  constexpr int AL = MF * KSL;   // A loads per lane per step

  __shared__ int IdxS[28 * BM];  // row 27 = zero-row dummy

  const int tid = threadIdx.x;
  const int lane = tid & 63;
  const int wave = tid >> 6;
  const int wm = wave / WN;
  const int wn = wave % WN;
  const int base = blockIdx.x * BM;
  const int q = lane >> 4;
  const int l16 = lane & 15;

  for (int f = tid; f < 28 * BM; f += 256) {
    int k = f / BM;
    int nn = base + (f % BM);
    IdxS[f] = (k < 27 && nn < nr) ? nbr[(size_t)k * nr + nn] : nr;
  }
  __syncthreads();

  const unsigned short* bbase = Bp + ((size_t)q * COUT + wn * WCOLS + l16) * 8;

  bf16x8 bA[NB], bB[NB], aA[AL], aB[AL];

  auto loadB = [&](bf16x8(&dst)[NB], int s) {
    const int k0 = s / H;
    const int k = (k0 > 26) ? 26 : k0;
    const int hh = s % H;
#pragma unroll
    for (int ks = 0; ks < KSL; ++ks)
#pragma unroll
      for (int j = 0; j < NF; ++j) {
        const int ksg = hh * KSL + ks;
        dst[ks * NF + j] = *(const bf16x8*)(
            bbase + ((size_t)k * CIN * COUT) + ((size_t)(ksg * 4) * COUT + j * 16) * 8);
      }
  };

  auto loadA = [&](bf16x8(&dst)[AL], int s) {
    const int k = s / H;  // k==27 -> dummy zero-row idx
    const int hh = s % H;
#pragma unroll
    for (int i = 0; i < MF; ++i) {
      int r = wm * WROWS + i * 16 + l16;
      int g = IdxS[k * BM + r];
      const unsigned short* src = X + (size_t)g * CIN + hh * BK + q * 8;
#pragma unroll
      for (int ks = 0; ks < KSL; ++ks)
        dst[i * KSL + ks] = *(const bf16x8*)(src + ks * 32);
    }
  };

  f32x4 acc[MF][NF] = {};

  auto mfmaStep = [&](const bf16x8(&af)[AL], const bf16x8(&bf)[NB]) {
#pragma unroll
    for (int ks = 0; ks < KSL; ++ks)
#pragma unroll
      for (int i = 0; i < MF; ++i)
#pragma unroll
        for (int j = 0; j < NF; ++j)
          acc[i][j] = __builtin_amdgcn_mfma_f32_16x16x32_bf16(
              af[i * KSL + ks], bf[ks * NF + j], acc[i][j], 0, 0, 0);
  };

  // ---- prologue: A(0)+B(0) in flight ----
  loadB(bA, 0);
  loadA(aA, 0);

#pragma unroll 1
  for (int s = 0; s + 1 < S; s += 2) {
    // ---- even half: compute s, prefetch s+1 ----
    loadB(bB, s + 1);
    loadA(aB, s + 1);
    waitvm<NB + AL>();  // s landed; s+1 stays in flight
    BARRIER();
    mfmaStep(aA, bA);
    // ---- odd half: compute s+1, prefetch s+2 (s+2==S -> dummy zero row) ----
    loadB(bA, s + 2);
    loadA(aA, s + 2);
    waitvm<NB + AL>();
    BARRIER();
    mfmaStep(aB, bB);
  }
  if constexpr (S & 1) {
    waitvm<0>();
    BARRIER();
    mfmaStep(aA, bA);
  }

  // ---- epilogue ----
#pragma unroll
  for (int i = 0; i < MF; ++i)
#pragma unroll
    for (int j = 0; j < NF; ++j)
#pragma unroll
      for (int r = 0; r < 4; ++r) {
        int row = base + wm * WROWS + i * 16 + q * 4 + r;
        int col = wn * WCOLS + j * 16 + l16;
        if (row < nr) {
          float v = acc[i][j][r];
          if constexpr (FINAL)
            OUT[(size_t)row * COUT + col] = v + DS[(size_t)row * COUT + col];
          else
            Y[(size_t)row * COUT + col] = f2bf(v);
        }
      }
}

// ---------------- launch ----------------
extern "C" void kernel_launch(void* const* d_in, const int* in_sizes, int n_in,
                              void* d_out, int out_size, void* d_ws, size_t ws_size,
                              hipStream_t stream) {
  const float* feats = (const float*)d_in[0];
  const float* W0 = (const float*)d_in[1];
  const float* W1 = (const float*)d_in[2];
  const float* W2 = (const float*)d_in[3];
  const int* nbr = (const int*)d_in[4];
  const int n = in_sizes[0] / 128;
  float* out = (float*)d_out;

  char* p = (char*)d_ws;
  auto take = [&](size_t bytes) {
    char* r = p;
    p += (bytes + 255) & ~(size_t)255;
    return r;
  };
  unsigned short* resB = (unsigned short*)take((size_t)(n + 1) * 128 * 2);
  unsigned short* y0 = (unsigned short*)take((size_t)(n + 1) * 128 * 2);
  unsigned short* y1 = (unsigned short*)take((size_t)(n + 1) * 32 * 2);
  float* ds = (float*)take((size_t)n * 32 * 4);
  unsigned short* p0 = (unsigned short*)take((size_t)27 * 128 * 128 * 2);
  unsigned short* p1 = (unsigned short*)take((size_t)27 * 128 * 32 * 2);
  unsigned short* p2 = (unsigned short*)take((size_t)27 * 32 * 32 * 2);

  prep_kernel<<<(n + 15) / 16, 256, 0, stream>>>(feats, resB, ds, n);
  pack_kernel<<<284, 256, 0, stream>>>(W0, W1, W2, p0, p1, p2);
  zero_tail<<<1, 128, 0, stream>>>(resB + (size_t)n * 128, y0 + (size_t)n * 128,
                                   y1 + (size_t)n * 32);
  const int gb128 = (n + 127) / 128;
  // conv0: 128->128. Round-5 winner exactly: BM=128, BK=64, PF=1, WM=1/WN=4.
  spconv<128, 128, 64, 128, 1, 1, 4, false, 3>
      <<<gb128, 256, 0, stream>>>(resB, p0, nbr, y0, nullptr, nullptr, n);
  // conv1: 128->32. Register-gather A (no LDS staging; rows wave-partitioned).
  spconv_reg<128, 32, 64, 128, 4, 1, false, 3>
      <<<gb128, 256, 0, stream>>>(y0, p1, nbr, y1, nullptr, nullptr, n);
  // conv2: 32->32. Register-gather A.
  spconv_reg<32, 32, 32, 128, 4, 1, true, 4>
      <<<gb128, 256, 0, stream>>>(y1, p2, nbr, nullptr, out, ds, n);
}